// Round 9
// baseline (3580.716 us; speedup 1.0000x reference)
//
#include <hip/hip_runtime.h>

#define NN 30000
#define EE 480000

// ---------- zero-fill fallback (ws too small diagnostic) ----------
__global__ __launch_bounds__(256) void k_zero(float* __restrict__ out, int n){
  int i = blockIdx.x*256 + threadIdx.x;
  if (i < n) out[i] = 0.f;
}

// ---------- node feature init: fA[N][288] (row0=node_l0, rest 0), hist=0 ----------
__global__ __launch_bounds__(256) void k_init(
    const float* __restrict__ nl0, float* __restrict__ fA, int* __restrict__ hist)
{
  int i = blockIdx.x*256 + threadIdx.x;   // exactly N*288
  int n = i/288; int r2 = i - n*288;
  fA[i] = (r2 < 32) ? nl0[(size_t)n*32 + r2] : 0.f;
  if (i < NN) hist[i] = 0;
}

__global__ __launch_bounds__(256) void k_hist(const int* __restrict__ dst, int* __restrict__ hist){
  int e = blockIdx.x*256 + threadIdx.x;
  if (e < EE) atomicAdd(&hist[dst[e]], 1);
}

// ---------- two-level exclusive scan over hist[NN] ----------
__global__ __launch_bounds__(1024) void k_scan1(const int* __restrict__ hist,
    int* __restrict__ offs, int* __restrict__ bsum, int n)
{
  __shared__ int sm[1024];
  int tid = threadIdx.x;
  int i = blockIdx.x*1024 + tid;
  int v = (i<n)? hist[i] : 0;
  sm[tid] = v; __syncthreads();
  for (int o=1;o<1024;o<<=1){
    int tv = (tid>=o)? sm[tid-o] : 0;
    __syncthreads();
    sm[tid] += tv;
    __syncthreads();
  }
  if (i<n) offs[i] = sm[tid]-v;           // block-local exclusive
  if (tid==1023) bsum[blockIdx.x] = sm[1023];
}
__global__ void k_scan2(int* __restrict__ bsum, int* __restrict__ offs, int nb, int n){
  if (threadIdx.x==0){
    int acc=0;
    for (int b=0;b<nb;b++){ int v=bsum[b]; bsum[b]=acc; acc+=v; }
    offs[n] = acc;
  }
}
__global__ __launch_bounds__(1024) void k_scan3(int* __restrict__ offs,
    const int* __restrict__ bsum, int* __restrict__ cursor, int n)
{
  int i = blockIdx.x*1024 + threadIdx.x;
  if (i<n){
    int v = offs[i] + bsum[blockIdx.x];
    offs[i] = v; cursor[i] = v;
  }
}

__global__ __launch_bounds__(256) void k_scatter(const int* __restrict__ dst,
    int* __restrict__ cursor, int* __restrict__ perm)
{
  int e = blockIdx.x*256 + threadIdx.x;
  if (e >= EE) return;
  int d = dst[e];
  int p = atomicAdd(&cursor[d], 1);
  perm[p] = e;
}

// ---------- per-node q projection ----------
__global__ __launch_bounds__(256) void k_q(const float* __restrict__ f_in,
    const float* __restrict__ Wqf, float* __restrict__ qn)
{
  int t = blockIdx.x*256 + threadIdx.x;   // N*32 exactly
  int n = t>>5, c = t&31;
  const float* f0 = f_in + (size_t)n*288;
  float acc=0.f;
  #pragma unroll
  for (int ci=0;ci<32;ci++) acc = fmaf(f0[ci], Wqf[ci*32+c], acc);
  qn[t] = acc;
}

// ---------- pass A: channel-parallel per-edge logits (+ optional h cache) ----------
// half-wave (32 lanes) = 1 edge, lane c = channel c; dst-sorted (perm) order.
// 15000 blocks x 32 edges; 4 iterations of 8 concurrent edges.
__global__ __launch_bounds__(256) void k_edge(
    const float* __restrict__ pos, const float* __restrict__ ef,
    const int* __restrict__ src, const int* __restrict__ dst,
    const int* __restrict__ perm,
    const float* __restrict__ f_in, const float* __restrict__ qn,
    const float* __restrict__ Wr1g, const float* __restrict__ br1g,
    const float* __restrict__ Wr2g, const float* __restrict__ Wkg,
    float* __restrict__ logitsP, float* __restrict__ hbuf,
    int use_h, int first)
{
  __shared__ float W1L[1056];   // [33][32]
  __shared__ float W2L[7168];   // [32][224]
  __shared__ float WKL[1024];   // [32][32]
  __shared__ float B1L[32];
  int tid = threadIdx.x;
  for (int i=tid;i<1056;i+=256) W1L[i]=Wr1g[i];
  for (int i=tid;i<7168;i+=256) W2L[i]=Wr2g[i];
  for (int i=tid;i<1024;i+=256) WKL[i]=Wkg[i];
  if (tid<32) B1L[tid]=br1g[tid];
  __syncthreads();

  int lane = tid & 63;
  int wv   = tid >> 6;
  int c    = lane & 31;
  int half = lane >> 5;
  int hh   = c >> 3;

  #pragma unroll 1
  for (int it=0; it<4; ++it){
    int p = blockIdx.x*32 + it*8 + wv*2 + half;   // 15000*32 = 480000 exact
    int e = perm[p];
    int s = src[e], d = dst[e];
    float px = pos[d*3+0]-pos[s*3+0];
    float py = pos[d*3+1]-pos[s*3+1];
    float pz = pos[d*3+2]-pos[s*3+2];
    float rr = sqrtf(px*px+py*py+pz*pz+1e-8f);
    float inv = 1.f/rr;
    float y1x=px*inv, y1y=py*inv, y1z=pz*inv;
    float y2a=y1x*y1y, y2b=y1y*y1z, y2c=3.f*y1z*y1z-1.f, y2d=y1x*y1z, y2e=y1x*y1x-y1y*y1y;

    float rv = ef[(size_t)e*32 + c];                 // coalesced 128B row
    float h = B1L[c] + rr*W1L[c];
    #pragma unroll
    for (int j=0;j<32;j++) h = fmaf(__shfl(rv,j,32), W1L[(1+j)*32+c], h);
    h = fmaxf(h, 0.f);
    if (use_h) hbuf[(size_t)p*32 + c] = h;

    float w0=0.f, w1=0.f, w2=0.f;
    #pragma unroll
    for (int ci=0;ci<32;ci++){
      float hb = __shfl(h,ci,32);
      const float* wr = &W2L[ci*224 + c];
      w0 = fmaf(hb, wr[0],  w0);
      if (!first){
        w1 = fmaf(hb, wr[32], w1);
        w2 = fmaf(hb, wr[64], w2);
      }
    }
    const float* fs = f_in + (size_t)s*288;
    float m0 = w0 * fs[c];
    if (!first){
      float g1 = fs[32+c]*y1x + fs[64+c]*y1y + fs[96+c]*y1z;
      float g2 = fs[128+c]*y2a + fs[160+c]*y2b + fs[192+c]*y2c + fs[224+c]*y2d + fs[256+c]*y2e;
      m0 += w1*g1 + w2*g2;
    }
    float kk = 0.f;
    #pragma unroll
    for (int ci=0;ci<32;ci++) kk = fmaf(__shfl(m0,ci,32), WKL[ci*32+c], kk);

    float pr = qn[(size_t)d*32 + c] * kk;
    pr += __shfl_xor(pr,1,8); pr += __shfl_xor(pr,2,8); pr += __shfl_xor(pr,4,8);
    if ((c&7)==0) logitsP[(size_t)p*4 + hh] = pr * 0.35355339059327373f; // 1/sqrt(8)
  }
}

// ---------- pass B: block-per-node softmax + aggregation ----------
// 8 half-waves stride the node's edge list; partial A[9] per half; LDS tree-reduce.
__global__ __launch_bounds__(256) void k_agg(
    const float* __restrict__ pos, const float* __restrict__ ef,
    const int* __restrict__ src, const int* __restrict__ dst,
    const int* __restrict__ offs, const int* __restrict__ perm,
    const float* __restrict__ f_in, const float* __restrict__ logitsP,
    const float* __restrict__ Wr1g, const float* __restrict__ br1g,
    const float* __restrict__ Wr2g,
    float* __restrict__ aggG, const float* __restrict__ hbuf,
    int use_h, int first)
{
  __shared__ float W1L[1056];
  __shared__ float W2L[7168];
  __shared__ float B1L[32];
  __shared__ float red[4][288];
  int tid = threadIdx.x;
  for (int i=tid;i<7168;i+=256) W2L[i]=Wr2g[i];
  if (!use_h){
    for (int i=tid;i<1056;i+=256) W1L[i]=Wr1g[i];
    if (tid<32) B1L[tid]=br1g[tid];
  }
  __syncthreads();

  int lane = tid & 63;
  int wv   = tid >> 6;
  int c    = lane & 31;
  int half = lane >> 5;
  int hh   = c >> 3;
  int hw   = wv*2 + half;                // 0..7
  int n = blockIdx.x;                    // block per node
  int start = offs[n], end = offs[n+1];

  // exact segment softmax stats (redundant per wave; slice is contiguous)
  float m0=-1e30f,m1=-1e30f,m2=-1e30f,m3=-1e30f;
  for (int p=start+lane;p<end;p+=64){
    float4 lv = *(const float4*)(logitsP + (size_t)p*4);
    m0=fmaxf(m0,lv.x); m1=fmaxf(m1,lv.y); m2=fmaxf(m2,lv.z); m3=fmaxf(m3,lv.w);
  }
  #pragma unroll
  for (int mk=1;mk<64;mk<<=1){
    m0=fmaxf(m0,__shfl_xor(m0,mk)); m1=fmaxf(m1,__shfl_xor(m1,mk));
    m2=fmaxf(m2,__shfl_xor(m2,mk)); m3=fmaxf(m3,__shfl_xor(m3,mk));
  }
  float s0=0.f,s1=0.f,s2=0.f,s3=0.f;
  for (int p=start+lane;p<end;p+=64){
    float4 lv = *(const float4*)(logitsP + (size_t)p*4);
    s0 += __expf(lv.x-m0); s1 += __expf(lv.y-m1);
    s2 += __expf(lv.z-m2); s3 += __expf(lv.w-m3);
  }
  #pragma unroll
  for (int mk=1;mk<64;mk<<=1){
    s0 += __shfl_xor(s0,mk); s1 += __shfl_xor(s1,mk);
    s2 += __shfl_xor(s2,mk); s3 += __shfl_xor(s3,mk);
  }
  float i0=1.f/(s0+1e-8f), i1=1.f/(s1+1e-8f), i2=1.f/(s2+1e-8f), i3=1.f/(s3+1e-8f);
  float mh = (hh==0)?m0:((hh==1)?m1:((hh==2)?m2:m3));
  float ih = (hh==0)?i0:((hh==1)?i1:((hh==2)?i2:i3));

  float A[9];
  #pragma unroll
  for (int j=0;j<9;j++) A[j]=0.f;

  #pragma unroll 1
  for (int p=start+hw; p<end; p+=8){
    int e = perm[p];
    int s = src[e], d = dst[e];
    float px = pos[d*3+0]-pos[s*3+0];
    float py = pos[d*3+1]-pos[s*3+1];
    float pz = pos[d*3+2]-pos[s*3+2];
    float rr = sqrtf(px*px+py*py+pz*pz+1e-8f);
    float inv = 1.f/rr;
    float y1x=px*inv, y1y=py*inv, y1z=pz*inv;
    float y2a=y1x*y1y, y2b=y1y*y1z, y2c=3.f*y1z*y1z-1.f, y2d=y1x*y1z, y2e=y1x*y1x-y1y*y1y;

    float h;
    if (use_h){
      h = hbuf[(size_t)p*32 + c];
    } else {
      float rv = ef[(size_t)e*32 + c];
      h = B1L[c] + rr*W1L[c];
      #pragma unroll
      for (int j=0;j<32;j++) h = fmaf(__shfl(rv,j,32), W1L[(1+j)*32+c], h);
      h = fmaxf(h, 0.f);
    }

    float w0=0.f,w1=0.f,w2=0.f,w3=0.f,w4=0.f,w5=0.f,w6=0.f;
    #pragma unroll
    for (int ci=0;ci<32;ci++){
      float hb = __shfl(h,ci,32);
      const float* wr = &W2L[ci*224 + c];
      w0 = fmaf(hb, wr[0],   w0);
      w3 = fmaf(hb, wr[96],  w3);
      w5 = fmaf(hb, wr[160], w5);
      if (!first){
        w1 = fmaf(hb, wr[32],  w1);
        w2 = fmaf(hb, wr[64],  w2);
        w4 = fmaf(hb, wr[128], w4);
        w6 = fmaf(hb, wr[192], w6);
      }
    }
    const float* fs = f_in + (size_t)s*288;
    float f0 = fs[c];
    float f1a=0.f,f1b=0.f,f1c=0.f, f2a=0.f,f2b=0.f,f2c=0.f,f2d=0.f,f2e=0.f;
    if (!first){
      f1a=fs[32+c]; f1b=fs[64+c]; f1c=fs[96+c];
      f2a=fs[128+c]; f2b=fs[160+c]; f2c=fs[192+c]; f2d=fs[224+c]; f2e=fs[256+c];
    }
    float m0v = w0*f0;
    if (!first){
      m0v += w1*(f1a*y1x+f1b*y1y+f1c*y1z)
           + w2*(f2a*y2a+f2b*y2b+f2c*y2c+f2d*y2d+f2e*y2e);
    }
    float lgv = logitsP[(size_t)p*4 + hh];
    float a = __expf(lgv - mh) * ih;

    A[0] = fmaf(a, m0v, A[0]);
    A[1] = fmaf(a, w3*f0*y1x + w4*f1a, A[1]);
    A[2] = fmaf(a, w3*f0*y1y + w4*f1b, A[2]);
    A[3] = fmaf(a, w3*f0*y1z + w4*f1c, A[3]);
    A[4] = fmaf(a, w5*f0*y2a + w6*f2a, A[4]);
    A[5] = fmaf(a, w5*f0*y2b + w6*f2b, A[5]);
    A[6] = fmaf(a, w5*f0*y2c + w6*f2c, A[6]);
    A[7] = fmaf(a, w5*f0*y2d + w6*f2d, A[7]);
    A[8] = fmaf(a, w5*f0*y2e + w6*f2e, A[8]);
  }
  // merge the two halves of each wave (same channel c)
  #pragma unroll
  for (int j=0;j<9;j++) A[j] += __shfl_xor(A[j],32,64);
  if (half==0){
    #pragma unroll
    for (int j=0;j<9;j++) red[wv][j*32+c] = A[j];
  }
  __syncthreads();
  // FIX (R8 bug): block has 256 threads but 288 outputs — stride the write.
  for (int i=tid; i<288; i+=256)
    aggG[(size_t)n*288 + i] = red[0][i]+red[1][i]+red[2][i]+red[3][i];
}

// ---------- node update: f_out = [agg0@Ws0 + f0@Wsk, agg1@Ws1, agg2@Ws2] ----------
__global__ __launch_bounds__(256) void k_update(
    const float* __restrict__ aggG, const float* __restrict__ f_in,
    const float* __restrict__ Ws0, const float* __restrict__ Ws1,
    const float* __restrict__ Ws2, const float* __restrict__ Wsk,
    float* __restrict__ f_out)
{
  __shared__ float wL[4096];
  __shared__ float agL[8][297];
  __shared__ float f0L[8][33];
  int tid = threadIdx.x;
  int nb = blockIdx.x*8;
  for (int i=tid;i<1024;i+=256){
    wL[i]=Ws0[i]; wL[1024+i]=Ws1[i]; wL[2048+i]=Ws2[i]; wL[3072+i]=Wsk[i];
  }
  for (int i=tid;i<2304;i+=256){
    int nl=i/288, F=i-nl*288, r=F>>5, cc=F&31;
    agL[nl][r*33+cc] = aggG[(size_t)(nb+nl)*288 + F];
  }
  { int nl=tid>>5, cc=tid&31; f0L[nl][cc] = f_in[(size_t)(nb+nl)*288 + cc]; }
  __syncthreads();
  int nl = tid>>5, o = tid&31;
  size_t obase = (size_t)(nb+nl)*288;
  #pragma unroll 1
  for (int r=0;r<9;r++){
    const float* W = (r==0)? wL : ((r<4)? wL+1024 : wL+2048);
    float acc=0.f;
    #pragma unroll
    for (int cc=0;cc<32;cc++) acc = fmaf(agL[nl][r*33+cc], W[cc*32+o], acc);
    if (r==0){
      #pragma unroll
      for (int cc=0;cc<32;cc++) acc = fmaf(f0L[nl][cc], wL[3072 + cc*32+o], acc);
    }
    f_out[obase + r*32 + o] = acc;
  }
}

// ---------- output head (f32 out) ----------
__global__ __launch_bounds__(256) void k_out(
    const float* __restrict__ f_in, const float* __restrict__ Wout,
    const float* __restrict__ Wc, float* __restrict__ out)
{
  __shared__ float sh[8][33];
  int tid = threadIdx.x;
  int nl = tid>>5, c = tid&31;
  int n = blockIdx.x*8 + nl;
  const float* f0 = f_in + (size_t)n*288;
  float acc=0.f;
  #pragma unroll
  for (int ci=0;ci<32;ci++) acc = fmaf(f0[ci], Wout[ci*32+c], acc);
  out[(size_t)n*32 + c] = acc;
  sh[nl][c] = acc;
  __syncthreads();
  if (tid < 120){
    int nl2 = tid/15, j = tid%15;
    int n2 = blockIdx.x*8 + nl2;
    float a = 0.f;
    #pragma unroll
    for (int ci=0;ci<32;ci++) a = fmaf(sh[nl2][ci], Wc[ci*15+j], a);
    out[(size_t)NN*32 + (size_t)n2*15 + j] = a;
  }
}

extern "C" void kernel_launch(void* const* d_in, const int* in_sizes, int n_in,
                              void* d_out, int out_size, void* d_ws, size_t ws_size,
                              hipStream_t stream)
{
  (void)in_sizes; (void)n_in;
  const float* pos       = (const float*)d_in[0];
  const float* node_l0   = (const float*)d_in[1];
  const float* edge_feat = (const float*)d_in[2];
  const int* esrc = (const int*)d_in[3];
  const int* edst = (const int*)d_in[4];
  const float* Wr1  = (const float*)d_in[5];
  const float* br1  = (const float*)d_in[6];
  const float* Wr2  = (const float*)d_in[7];
  const float* Wq   = (const float*)d_in[8];
  const float* Wk   = (const float*)d_in[9];
  const float* Ws0  = (const float*)d_in[10];
  const float* Ws1  = (const float*)d_in[11];
  const float* Ws2  = (const float*)d_in[12];
  const float* Wsk  = (const float*)d_in[13];
  const float* Wout = (const float*)d_in[14];
  const float* Wc   = (const float*)d_in[15];

  char* ws = (char*)d_ws;
  size_t off = 0;
  auto take = [&](size_t bytes)->char*{
    char* p = ws + off;
    off += (bytes + 255) & ~(size_t)255;
    return p;
  };
  float* fA      = (float*)take((size_t)NN*288*4);   // 34.56 MB
  float* fB      = (float*)take((size_t)NN*288*4);   // 34.56 MB
  float* qn      = (float*)take((size_t)NN*32*4);    //  3.84 MB
  int*   hist    = (int*)  take((size_t)NN*4);
  int*   offs    = (int*)  take((size_t)(NN+1)*4);
  int*   cursor  = (int*)  take((size_t)NN*4);
  int*   bsum    = (int*)  take((size_t)64*4);
  int*   perm    = (int*)  take((size_t)EE*4);       //  1.92 MB
  float* logitsP = (float*)take((size_t)EE*4*4);     //  7.68 MB
  size_t need_base = off;                             // ~83 MB (proven OK)
  float* hbuf    = (float*)take((size_t)EE*32*4);    // +61.44 MB (optional)
  int use_h = (ws_size >= off) ? 1 : 0;

  if (ws_size < need_base){
    k_zero<<<(out_size+255)/256,256,0,stream>>>((float*)d_out, out_size);
    return;
  }

  k_init<<<33750,256,0,stream>>>(node_l0, fA, hist);
  k_hist<<<1875,256,0,stream>>>(edst, hist);
  k_scan1<<<30,1024,0,stream>>>(hist, offs, bsum, NN);
  k_scan2<<<1,32,0,stream>>>(bsum, offs, 30, NN);
  k_scan3<<<30,1024,0,stream>>>(offs, bsum, cursor, NN);
  k_scatter<<<1875,256,0,stream>>>(edst, cursor, perm);

  float* fi = fA; float* fo = fB;
  for (int l=0; l<2; ++l){
    int first = (l==0)?1:0;
    k_q<<<3750,256,0,stream>>>(fi, Wq + l*1024, qn);
    k_edge<<<15000,256,0,stream>>>(pos, edge_feat, esrc, edst, perm,
        fi, qn,
        Wr1 + l*1056, br1 + l*32, Wr2 + l*7168, Wk + l*1024,
        logitsP, hbuf, use_h, first);
    k_agg<<<30000,256,0,stream>>>(pos, edge_feat, esrc, edst, offs, perm,
        fi, logitsP,
        Wr1 + l*1056, br1 + l*32, Wr2 + l*7168,
        fo, hbuf, use_h, first);
    k_update<<<3750,256,0,stream>>>(fo, fi,
        Ws0 + l*1024, Ws1 + l*1024, Ws2 + l*1024, Wsk + l*1024, fo);
    float* tmp = fi; fi = fo; fo = tmp;
  }
  k_out<<<3750,256,0,stream>>>(fi, Wout, Wc, (float*)d_out);
}